// Round 14
// baseline (401.238 us; speedup 1.0000x reference)
//
#include <hip/hip_runtime.h>
#include <hip/hip_bf16.h>
#include <math.h>

typedef unsigned short ushort_t;
typedef __attribute__((ext_vector_type(8))) short short8;
typedef __attribute__((ext_vector_type(4))) short s4v;
typedef __attribute__((ext_vector_type(4))) float float4v;

#define HID 1024
#define NH 8
#define DH 128
#define CHUNK 12
#define PAST 12
#define CTX 24
#define NPOS 25
#define QKVW 3072

__device__ __forceinline__ float bf2f(ushort_t b){
  union{unsigned int u; float f;} x; x.u = ((unsigned int)b)<<16; return x.f;
}
__device__ __forceinline__ ushort_t f2bf(float f){
  union{float f; unsigned int u;} x; x.f = f;
  unsigned int u = x.u;
  unsigned int r = u + 0x7fffu + ((u>>16)&1u);
  return (ushort_t)(r>>16);
}

__device__ __forceinline__ void gload16(const ushort_t* g, ushort_t* l){
  __builtin_amdgcn_global_load_lds(
      (const __attribute__((address_space(1))) unsigned int*)g,
      (__attribute__((address_space(3))) unsigned int*)l,
      16, 0, 0);
}

// one launch: hs -> hsb, Wq|Wk|Wv -> Wcat, Wpost -> Wpb (f32 -> bf16)
__global__ __launch_bounds__(256) void cvt_all(
    const float* __restrict__ hs, const float* __restrict__ Wq,
    const float* __restrict__ Wk, const float* __restrict__ Wv,
    const float* __restrict__ Wp, ushort_t* __restrict__ hsb,
    ushort_t* __restrict__ Wcat, ushort_t* __restrict__ Wpb, int nhs4)
{
  const int W4 = 262144;               // (1024*1024)/4
  const int total = nhs4 + 4*W4;
  for (int i = blockIdx.x*256 + threadIdx.x; i < total; i += gridDim.x*256){
    const float4v* src; s4v* dst; int off;
    if (i < nhs4){ src = (const float4v*)hs; dst = (s4v*)hsb; off = i; }
    else {
      int j = i - nhs4; int seg = j >> 18; off = j & (W4-1);
      src = (const float4v*)(seg==0?Wq:seg==1?Wk:seg==2?Wv:Wp);
      dst = (seg<3) ? ((s4v*)Wcat) + (size_t)seg*W4 : (s4v*)Wpb;
    }
    float4v v = src[off];
    s4v o;
#pragma unroll
    for (int j2=0;j2<4;j2++) o[j2] = (short)f2bf(v[j2]);
    dst[off] = o;
  }
}

// ===== QKV GEMM: 256x128 tile, wave=128x64 (acc 8x4), 3-ring counted vmcnt =====
// Per BK=32 tile/wave: 12 ds_read_b128 + 32 MFMA (0.375 KB/MFMA vs 0.5 at 64x64)
// -> ~25% lower LDS-read traffic (the measured binding resource).
// Ledger: 6 gload16/thread/tile, lead 2 -> 12 outstanding at entry;
// vmcnt(6) retires exactly tile t; vmcnt(0) only at the last tile.
// Bank placement (r12-proven): row r, global 16B-slot s at phys slot
// s^((r>>1)&3); lane-constant on reads since all row bases are mult of 16.
template<int MODE>
__global__ __launch_bounds__(256) void gemmw(
    const ushort_t* __restrict__ A, const ushort_t* __restrict__ W,
    ushort_t* __restrict__ C, int M, int N, int K,
    const float* __restrict__ pds, float qsc, float ksc)
{
  const int nwg  = gridDim.x;
  const int orig = blockIdx.x;
  const int qch  = nwg >> 3, rch = nwg & 7;
  const int xcd  = orig & 7, idx = orig >> 3;
  const int bid  = (xcd < rch ? xcd*(qch+1) : rch*(qch+1) + (xcd-rch)*qch) + idx;

  const int NT = N >> 7;               // 128-wide n-tiles (fastest)
  const int m0 = (bid / NT) * 256;
  const int n0 = (bid % NT) * 128;

  const int tid  = threadIdx.x;
  const int w    = tid >> 6, lane = tid & 63;
  const int wm   = w >> 1, wn = w & 1;   // wave tile: 128(m) x 64(n)
  const int lr   = lane & 15;
  const int lg   = lane >> 4;

  __shared__ ushort_t slab[3*12288];   // 72KB: 3 x (A[256x32] + B[128x32])
  ushort_t* a0 = slab;              ushort_t* b0 = slab + 8192;
  ushort_t* a1 = slab + 12288;      ushort_t* b1 = slab + 20480;
  ushort_t* a2 = slab + 24576;      ushort_t* b2 = slab + 32768;

  float4v acc[8][4];
#pragma unroll
  for (int i=0;i<8;i++)
#pragma unroll
    for (int j=0;j<4;j++) acc[i][j] = (float4v)0.0f;

  // staging inverse permutation: lane l -> row l>>2, global slot (l&3)^((l>>3)&3)
  const int sr = lane >> 2;
  const int sc = ((lane & 3) ^ ((lane >> 3) & 3)) * 8;
  // read-side lane-constant permuted slot offset (ushorts)
  const int ps = (lg ^ ((lr >> 1) & 3)) * 8;

  const ushort_t* Ag0 = A + (size_t)(m0 +       w*16 + sr)*K + sc;
  const ushort_t* Ag1 = A + (size_t)(m0 +  64 + w*16 + sr)*K + sc;
  const ushort_t* Ag2 = A + (size_t)(m0 + 128 + w*16 + sr)*K + sc;
  const ushort_t* Ag3 = A + (size_t)(m0 + 192 + w*16 + sr)*K + sc;
  const ushort_t* Bg0 = W + (size_t)(n0 +       w*16 + sr)*K + sc;
  const ushort_t* Bg1 = W + (size_t)(n0 +  64 + w*16 + sr)*K + sc;

#define STAGE(Abuf, Bbuf, kt) do {                      \
    gload16(Ag0 + (kt), &(Abuf)[(      w*16)*32]);      \
    gload16(Ag1 + (kt), &(Abuf)[( 64 + w*16)*32]);      \
    gload16(Ag2 + (kt), &(Abuf)[(128 + w*16)*32]);      \
    gload16(Ag3 + (kt), &(Abuf)[(192 + w*16)*32]);      \
    gload16(Bg0 + (kt), &(Bbuf)[(      w*16)*32]);      \
    gload16(Bg1 + (kt), &(Bbuf)[( 64 + w*16)*32]);      \
  } while(0)

#define COMPUTE(Abuf, Bbuf) do {                                             \
    short8 bfr[4];                                                           \
    _Pragma("unroll")                                                        \
    for (int j=0;j<4;j++)                                                    \
      bfr[j] = *(const short8*)&(Bbuf)[(wn*64 + j*16 + lr)*32 + ps];         \
    __builtin_amdgcn_s_setprio(1);                                           \
    _Pragma("unroll")                                                        \
    for (int mi=0; mi<8; mi++){                                              \
      short8 afr = *(const short8*)&(Abuf)[(wm*128 + mi*16 + lr)*32 + ps];   \
      _Pragma("unroll")                                                      \
      for (int j=0;j<4;j++)                                                  \
        acc[mi][j] = __builtin_amdgcn_mfma_f32_16x16x32_bf16(afr, bfr[j], acc[mi][j], 0,0,0); \
    }                                                                        \
    __builtin_amdgcn_s_setprio(0);                                           \
  } while(0)

  const int nt = K >> 5;               // 32 K-tiles
  STAGE(a0, b0, 0);
  STAGE(a1, b1, 32);

  for (int t = 0; t < nt; ++t){
    if (t == nt-1) asm volatile("s_waitcnt vmcnt(0)" ::: "memory");
    else           asm volatile("s_waitcnt vmcnt(6)" ::: "memory");
    asm volatile("s_barrier" ::: "memory");
    if (t+2 < nt) STAGE(a2, b2, (t+2)*32);
    COMPUTE(a0, b0);
    ushort_t* ta = a0; a0 = a1; a1 = a2; a2 = ta;
    ushort_t* tb = b0; b0 = b1; b1 = b2; b2 = tb;
  }
#undef STAGE
#undef COMPUTE

  __syncthreads();

  // coalesced epilogue: C-tile 256x128 bf16 (64KB) in slab
#pragma unroll
  for (int j=0;j<4;j++){
    const int col = wn*64 + j*16 + lr;
    float scale = 1.0f;
    if (MODE==1){
      const int gcol = n0 + col;
      if (gcol < 1024){ float p = pds[gcol & (DH-1)]; scale = qsc * log1pf(expf(p)); }
      else if (gcol < 2048) scale = ksc;
    }
#pragma unroll
    for (int mi=0; mi<8; mi++){
      const int row = wm*128 + mi*16 + lg*4;
#pragma unroll
      for (int r=0;r<4;r++)
        slab[(row + r)*128 + col] = f2bf(acc[mi][j][r] * scale);
    }
  }
  __syncthreads();
  ushort_t* Crow = C + (size_t)m0*N + n0;
  const int rr = tid >> 4, sl = (tid & 15)*8;
#pragma unroll
  for (int it=0; it<16; ++it){
    const int row = it*16 + rr;
    *(short8*)&Crow[(size_t)row*N + sl] = *(const short8*)&slab[row*128 + sl];
  }
}

// ===== r12 gemm3 (16x16 core, 2-way placement) — out-projection =====
template<int MODE, int OUTF>
__global__ __launch_bounds__(256) void gemm3(
    const ushort_t* __restrict__ A, const ushort_t* __restrict__ W,
    void* __restrict__ Cv, int M, int N, int K,
    const float* __restrict__ pds, float qsc, float ksc)
{
  const int nwg  = gridDim.x;
  const int orig = blockIdx.x;
  const int qch  = nwg >> 3, rch = nwg & 7;
  const int xcd  = orig & 7, idx = orig >> 3;
  const int bid  = (xcd < rch ? xcd*(qch+1) : rch*(qch+1) + (xcd-rch)*qch) + idx;

  const int NT = N >> 7;
  const int m0 = (bid / NT) * 128;
  const int n0 = (bid % NT) * 128;

  const int tid  = threadIdx.x;
  const int w    = tid >> 6, lane = tid & 63;
  const int wm   = w >> 1, wn = w & 1;
  const int lr   = lane & 15;
  const int lg   = lane >> 4;

  __shared__ ushort_t slab[6*128*32];
  ushort_t* a0 = slab;                 ushort_t* b0 = slab + 128*32;
  ushort_t* a1 = slab + 2*128*32;      ushort_t* b1 = slab + 3*128*32;
  ushort_t* a2 = slab + 4*128*32;      ushort_t* b2 = slab + 5*128*32;

  float4v acc[4][4];
#pragma unroll
  for (int i=0;i<4;i++)
#pragma unroll
    for (int j=0;j<4;j++) acc[i][j] = (float4v)0.0f;

  const int sr = lane >> 2;
  const int sc = ((lane & 3) ^ ((lane >> 3) & 3)) * 8;
  const int fidx = ((lr >> 1)*8 + (lr & 1)*4 + (lg ^ ((lr >> 1) & 3))) * 8;

  const ushort_t* Ab0 = A + (size_t)(m0 + w*16      + sr)*K + sc;
  const ushort_t* Ab1 = A + (size_t)(m0 + 64 + w*16 + sr)*K + sc;
  const ushort_t* Bb0 = W + (size_t)(n0 + w*16      + sr)*K + sc;
  const ushort_t* Bb1 = W + (size_t)(n0 + 64 + w*16 + sr)*K + sc;

#define STAGE(Abuf, Bbuf, kt) do {                    \
    gload16(Ab0 + (kt), &(Abuf)[(w*16)*32]);          \
    gload16(Ab1 + (kt), &(Abuf)[(64 + w*16)*32]);     \
    gload16(Bb0 + (kt), &(Bbuf)[(w*16)*32]);          \
    gload16(Bb1 + (kt), &(Bbuf)[(64 + w*16)*32]);     \
  } while(0)

#define COMPUTE(Abuf, Bbuf) do {                                             \
    short8 afr[4], bfr[4];                                                   \
    _Pragma("unroll")                                                        \
    for (int i=0;i<4;i++) afr[i] = *(const short8*)&(Abuf)[(wm*4 + i)*512 + fidx]; \
    _Pragma("unroll")                                                        \
    for (int j=0;j<4;j++) bfr[j] = *(const short8*)&(Bbuf)[(wn*4 + j)*512 + fidx]; \
    __builtin_amdgcn_s_setprio(1);                                           \
    _Pragma("unroll")                                                        \
    for (int i=0;i<4;i++)                                                    \
      _Pragma("unroll")                                                      \
      for (int j=0;j<4;j++)                                                  \
        acc[i][j] = __builtin_amdgcn_mfma_f32_16x16x32_bf16(afr[i], bfr[j], acc[i][j], 0,0,0); \
    __builtin_amdgcn_s_setprio(0);                                           \
  } while(0)

  const int nt = K >> 5;
  STAGE(a0, b0, 0);
  STAGE(a1, b1, 32);

  for (int t = 0; t < nt; ++t){
    if (t == nt-1) asm volatile("s_waitcnt vmcnt(0)" ::: "memory");
    else           asm volatile("s_waitcnt vmcnt(4)" ::: "memory");
    asm volatile("s_barrier" ::: "memory");
    if (t+2 < nt) STAGE(a2, b2, (t+2)*32);
    COMPUTE(a0, b0);
    ushort_t* ta = a0; a0 = a1; a1 = a2; a2 = ta;
    ushort_t* tb = b0; b0 = b1; b1 = b2; b2 = tb;
  }
#undef STAGE
#undef COMPUTE

  __syncthreads();

  if (OUTF == 0){
#pragma unroll
    for (int j=0;j<4;j++){
      const int col = wn*64 + j*16 + lr;
      float scale = 1.0f;
      if (MODE==1){
        const int gcol = n0 + col;
        if (gcol < 1024){ float p = pds[gcol & (DH-1)]; scale = qsc * log1pf(expf(p)); }
        else if (gcol < 2048) scale = ksc;
      }
#pragma unroll
      for (int i=0;i<4;i++){
        const int row = wm*64 + i*16 + lg*4;
#pragma unroll
        for (int r=0;r<4;r++)
          slab[(row + r)*128 + col] = f2bf(acc[i][j][r] * scale);
      }
    }
    __syncthreads();
    ushort_t* Crow = (ushort_t*)Cv + (size_t)m0*N + n0;
    const int rr = tid >> 4, sl = (tid & 15)*8;
#pragma unroll
    for (int it=0; it<8; ++it){
      const int row = it*16 + rr;
      *(short8*)&Crow[(size_t)row*N + sl] = *(const short8*)&slab[row*128 + sl];
    }
  } else {
    float* smf = (float*)slab;
    float* Crow = (float*)Cv + (size_t)m0*N + n0;
#pragma unroll
    for (int h2=0; h2<2; ++h2){
      __syncthreads();
      if (wm == h2){
#pragma unroll
        for (int j=0;j<4;j++){
          const int col = wn*64 + j*16 + lr;
#pragma unroll
          for (int i=0;i<4;i++){
            const int row = i*16 + lg*4;
#pragma unroll
            for (int r=0;r<4;r++)
              smf[(row + r)*128 + col] = acc[i][j][r];
          }
        }
      }
      __syncthreads();
      const int rr = tid >> 5, half = ((tid >> 4) & 1)*64, sl = (tid & 15)*4;
#pragma unroll
      for (int it=0; it<8; ++it){
        const int row = it*8 + rr;
        *(float4v*)&Crow[(size_t)(h2*64 + row)*N + half + sl] =
            *(const float4v*)&smf[row*128 + half + sl];
      }
    }
  }
}

// rel[25,1024] = pe[25,1024] @ Wrel^T, 2-way K-split + shfl combine
__global__ __launch_bounds__(256) void relk2(
    const float* __restrict__ pe, const float* __restrict__ Wrel,
    ushort_t* __restrict__ rel)
{
  int g = blockIdx.x*256 + threadIdx.x;
  int idx = g >> 1, par = g & 1;
  if (idx >= NPOS*HID) return;
  int p = idx >> 10, n = idx & 1023;
  const float* a = pe + p*HID + par*512;
  const float* w = Wrel + (size_t)n*HID + par*512;
  float s = 0.f;
  for (int k=0;k<512;k+=4){
    float4v av = *(const float4v*)(a+k);
    float4v wv = *(const float4v*)(w+k);
#pragma unroll
    for (int u=0;u<4;u++) s += av[u]*wv[u];
  }
  s += __shfl_xor(s, 1, 64);
  if (!par) rel[idx] = f2bf(s);
}

// MFMA attention, LDS lifetime-aliased: 49.6KB -> 3 blocks/CU. (r11/r12 passing)
__global__ __launch_bounds__(256) void attn_kernel(
  const ushort_t* __restrict__ qkv, const ushort_t* __restrict__ rel,
  ushort_t* __restrict__ o, int S)
{
  const int n0 = blockIdx.x * 4;
  const int b  = blockIdx.y, h = blockIdx.z;
  const int tid = threadIdx.x;
  const size_t bS = (size_t)b * S;

  __shared__ ushort_t lds[24800];
  ushort_t* ks = lds;
  ushort_t* vt = lds + 9248;
  float*    sB = (float*)(lds + 17952);
  ushort_t* rs = lds + 20448;
  float*    sA = (float*)(lds + 20448);

  const int base = n0*CHUNK - PAST;
  {
    const int r0 = tid >> 4;
    const int c0 = (tid & 15) * 8;
    for (int r = r0; r < 68; r += 16){
      int s = base + r;
      short8 kv = (short8)0, vv = (short8)0;
      if (r < 60 && s >= 0 && s < S){
        kv = *(const short8*)&qkv[(bS + s)*QKVW + 1024 + h*DH + c0];
        vv = *(const short8*)&qkv[(bS + s)*QKVW + 2048 + h*DH + c0];
      }
      *(short8*)&ks[r*136 + c0] = kv;
#pragma unroll
      for (int u=0;u<8;u++) vt[(c0+u)*68 + r] = (ushort_t)vv[u];
    }
    for (int r = r0; r < 32; r += 16){
      short8 rv = (short8)0;
      if (r < NPOS) rv = *(const short8*)&rel[r*HID + h*DH + c0];
      *(short8*)&rs[r*136 + c0] = rv;
    }
  }
  __syncthreads();

  const int w    = tid >> 6;
  const int lane = tid & 63;
  const int lr   = lane & 15;
  const int lg   = lane >> 4;

  float*    sAw = sA + w*312;
  float*    sBw = sB + w*312;
  ushort_t* Ppw = lds + w*640;

  int qrow = (n0 + w)*CHUNK + lr;
  if (qrow >= S) qrow = S - 1;
  const ushort_t* qp = qkv + (bS + qrow)*QKVW + h*DH + lg*8;
  short8 qf[4];
#pragma unroll
  for (int ks2=0; ks2<4; ks2++) qf[ks2] = *(const short8*)(qp + ks2*32);

  // BD = q @ rel^T
#pragma unroll
  for (int t0=0; t0<2; t0++){
    float4v acc = (float4v)0.0f;
#pragma unroll
    for (int ks2=0; ks2<4; ks2++){
      short8 rf = *(const short8*)&rs[(t0*16 + lr)*136 + ks2*32 + lg*8];
      acc = __builtin_amdgcn_mfma_f32_16x16x32_bf16(qf[ks2], rf, acc, 0,0,0);
    }
    const int p = t0*16 + lr;
#pragma unroll
    for (int reg=0; reg<4; reg++){
      int cr = lg*4 + reg;
      if (cr < CHUNK && p < NPOS) sBw[cr*26 + p] = acc[reg];
    }
  }
  __syncthreads();

  // AC = q @ k^T (sA aliases rs)
#pragma unroll
  for (int t0=0; t0<2; t0++){
    float4v acc = (float4v)0.0f;
#pragma unroll
    for (int ks2=0; ks2<4; ks2++){
      short8 kf = *(const short8*)&ks[(w*CHUNK + t0*16 + lr)*136 + ks2*32 + lg*8];
      acc = __builtin_amdgcn_mfma_f32_16x16x32_bf16(qf[ks2], kf, acc, 0,0,0);
    }
    const int t = t0*16 + lr;
#pragma unroll
    for (int reg=0; reg<4; reg++){
      int cr = lg*4 + reg;
      if (cr < CHUNK && t < CTX) sAw[cr*26 + t] = acc[reg];
    }
  }
  __syncthreads();

  if (lane < CHUNK) *(short8*)&Ppw[lane*40 + 24] = (short8)0;

  {
    const int c2 = lane >> 5;
    const int t  = lane & 31;
#pragma unroll
    for (int i=0;i<6;i++){
      int c = i*2 + c2;
      float x = -1e30f;
      if (t < CTX){
        int f = c*CTX + t;
        int r = f / NPOS, p = f - r*NPOS;
        x = sAw[c*26 + t] + sBw[r*26 + p];
        x = 50.0f * tanhf(x * 0.02f);
      }
      float m = x;
      for (int off=16; off>=1; off>>=1) m = fmaxf(m, __shfl_xor(m, off, 32));
      float e = (t < CTX) ? expf(x - m) : 0.0f;
      float s = e;
      for (int off=16; off>=1; off>>=1) s += __shfl_xor(s, off, 32);
      if (t < CTX) Ppw[c*40 + t] = f2bf(e / s);
    }
  }

  short8 pf = *(const short8*)&Ppw[lr*40 + lg*8];
  const int orow_base = (n0 + w)*CHUNK;
#pragma unroll
  for (int j=0; j<8; j++){
    int d  = j*16 + lr;
    int tb = w*CHUNK + lg*8;
    s4v b0 = *(const s4v*)&vt[d*68 + tb];
    s4v b1 = *(const s4v*)&vt[d*68 + tb + 4];
    short8 bf;
#pragma unroll
    for (int u=0;u<4;u++){ bf[u] = b0[u]; bf[u+4] = b1[u]; }
    float4v a = __builtin_amdgcn_mfma_f32_16x16x32_bf16(pf, bf, (float4v)0.0f, 0,0,0);
#pragma unroll
    for (int reg=0; reg<4; reg++){
      int cr = lg*4 + reg;
      if (cr < CHUNK)
        o[(bS + orow_base + cr)*HID + h*DH + j*16 + lr] = f2bf(a[reg]);
    }
  }
}

extern "C" void kernel_launch(void* const* d_in, const int* in_sizes, int n_in,
                              void* d_out, int out_size, void* d_ws, size_t ws_size,
                              hipStream_t stream)
{
  const float* hs    = (const float*)d_in[0];
  const float* pe    = (const float*)d_in[1];
  const float* Wq    = (const float*)d_in[2];
  const float* Wk    = (const float*)d_in[3];
  const float* Wv    = (const float*)d_in[4];
  const float* Wpost = (const float*)d_in[5];
  const float* Wrel  = (const float*)d_in[6];
  const float* pds   = (const float*)d_in[7];
  float* out = (float*)d_out;

  const int BS = in_sizes[0] / HID;   // 24576
  const int B  = 4;
  const int S  = BS / B;              // 6144
  const int nb = S / CHUNK;           // 512

  const size_t per = (size_t)BS * HID;
  const size_t wsz = (size_t)HID * HID;
  ushort_t* qkv  = (ushort_t*)d_ws;
  ushort_t* at   = qkv  + (size_t)BS * QKVW;
  ushort_t* rel  = at   + per;
  ushort_t* hsb  = rel  + (size_t)NPOS*HID;
  ushort_t* Wcat = hsb  + per;
  ushort_t* Wpb  = Wcat + 3*wsz;

  const float qsc = (float)(pow((double)DH, -0.5) / log(2.0));
  const float ksc = (float)(log(1.0 + exp(1.0)) / log(2.0));

  cvt_all<<<4096, 256, 0, stream>>>(hs, Wq, Wk, Wv, Wpost, hsb, Wcat, Wpb,
                                    (int)(per/4));
  relk2<<<200, 256, 0, stream>>>(pe, Wrel, rel);

  // fused QKV projection: 256x128 tile, wave 128x64
  gemmw<1><<<(BS/256)*(QKVW/128), 256, 0, stream>>>(
      hsb, Wcat, qkv, BS, QKVW, HID, pds, qsc, ksc);
  attn_kernel<<<dim3(nb/4, B, NH), 256, 0, stream>>>(qkv, rel, at, S);
  // output projection (r12 gemm3)
  gemm3<0,1><<<(BS/128)*(HID/128), 256, 0, stream>>>(
      at, Wpb, out, BS, HID, HID, nullptr, 1.0f, 1.0f);
}

// Round 15
// 389.367 us; speedup vs baseline: 1.0305x; 1.0305x over previous
//
#include <hip/hip_runtime.h>
#include <hip/hip_bf16.h>
#include <math.h>

typedef unsigned short ushort_t;
typedef __attribute__((ext_vector_type(8))) short short8;
typedef __attribute__((ext_vector_type(4))) short s4v;
typedef __attribute__((ext_vector_type(4))) float float4v;

#define HID 1024
#define NH 8
#define DH 128
#define CHUNK 12
#define PAST 12
#define CTX 24
#define NPOS 25
#define QKVW 3072

__device__ __forceinline__ float bf2f(ushort_t b){
  union{unsigned int u; float f;} x; x.u = ((unsigned int)b)<<16; return x.f;
}
__device__ __forceinline__ ushort_t f2bf(float f){
  union{float f; unsigned int u;} x; x.f = f;
  unsigned int u = x.u;
  unsigned int r = u + 0x7fffu + ((u>>16)&1u);
  return (ushort_t)(r>>16);
}

__device__ __forceinline__ void gload16(const ushort_t* g, ushort_t* l){
  __builtin_amdgcn_global_load_lds(
      (const __attribute__((address_space(1))) unsigned int*)g,
      (__attribute__((address_space(3))) unsigned int*)l,
      16, 0, 0);
}

// one launch: hs -> hsb, Wq|Wk|Wv -> Wcat, Wpost -> Wpb (f32 -> bf16)
__global__ __launch_bounds__(256) void cvt_all(
    const float* __restrict__ hs, const float* __restrict__ Wq,
    const float* __restrict__ Wk, const float* __restrict__ Wv,
    const float* __restrict__ Wp, ushort_t* __restrict__ hsb,
    ushort_t* __restrict__ Wcat, ushort_t* __restrict__ Wpb, int nhs4)
{
  const int W4 = 262144;               // (1024*1024)/4
  const int total = nhs4 + 4*W4;
  for (int i = blockIdx.x*256 + threadIdx.x; i < total; i += gridDim.x*256){
    const float4v* src; s4v* dst; int off;
    if (i < nhs4){ src = (const float4v*)hs; dst = (s4v*)hsb; off = i; }
    else {
      int j = i - nhs4; int seg = j >> 18; off = j & (W4-1);
      src = (const float4v*)(seg==0?Wq:seg==1?Wk:seg==2?Wv:Wp);
      dst = (seg<3) ? ((s4v*)Wcat) + (size_t)seg*W4 : (s4v*)Wpb;
    }
    float4v v = src[off];
    s4v o;
#pragma unroll
    for (int j2=0;j2<4;j2++) o[j2] = (short)f2bf(v[j2]);
    dst[off] = o;
  }
}

// ===== QKV GEMM: 128x128 tile, 8 waves of 32x64 (512 thr), 3-ring vmcnt(2) =====
// Same block-level totals as r12 (48 ds_read + 64 MFMA per K-tile, 48KB LDS,
// 2-way bank placement) but 2x wave concurrency: __launch_bounds__(512,6)
// -> 3 blocks/CU = 24 waves/CU (75%). Ledger: 2 gload16/thread/tile (1 A +
// 1 B), lead 2 -> 4 outstanding at entry; vmcnt(2) retires exactly tile t;
// vmcnt(0) only at the last tile. Placement: row r, global slot s at phys
// s^((r>>1)&3); staging inverse sr=lane>>2, sc=((l&3)^((l>>3)&3))*8 (valid:
// wave row base w*16 is a multiple of 8); read fidx identical to r12.
template<int MODE>
__global__ __launch_bounds__(512, 6) void gemm8w(
    const ushort_t* __restrict__ A, const ushort_t* __restrict__ W,
    ushort_t* __restrict__ C, int M, int N, int K,
    const float* __restrict__ pds, float qsc, float ksc)
{
  const int nwg  = gridDim.x;
  const int orig = blockIdx.x;
  const int qch  = nwg >> 3, rch = nwg & 7;
  const int xcd  = orig & 7, idx = orig >> 3;
  const int bid  = (xcd < rch ? xcd*(qch+1) : rch*(qch+1) + (xcd-rch)*qch) + idx;

  const int NT = N >> 7;
  const int m0 = (bid / NT) * 128;
  const int n0 = (bid % NT) * 128;

  const int tid  = threadIdx.x;
  const int w    = tid >> 6, lane = tid & 63;
  const int wm   = w >> 1, wn = w & 1;   // 4m x 2n -> wave tile 32x64
  const int lr   = lane & 15;
  const int lg   = lane >> 4;

  __shared__ ushort_t slab[6*4096];    // 48KB: 3 x (A[128x32] + B[128x32])
  ushort_t* a0 = slab;                 ushort_t* b0 = slab + 4096;
  ushort_t* a1 = slab + 8192;          ushort_t* b1 = slab + 12288;
  ushort_t* a2 = slab + 16384;         ushort_t* b2 = slab + 20480;

  float4v acc[2][4];
#pragma unroll
  for (int i=0;i<2;i++)
#pragma unroll
    for (int j=0;j<4;j++) acc[i][j] = (float4v)0.0f;

  // staging: wave w covers rows w*16..w*16+15; lane l -> row w*16+(l>>2),
  // global slot (l&3)^((l>>3)&3) (inverse of placement), LDS dest linear.
  const int sr = lane >> 2;
  const int sc = ((lane & 3) ^ ((lane >> 3) & 3)) * 8;
  // read-side lane-constant permuted offset (ushorts): lr*32 + perm_slot*8
  const int fidx = ((lr >> 1)*8 + (lr & 1)*4 + (lg ^ ((lr >> 1) & 3))) * 8;

  const ushort_t* Ag = A + (size_t)(m0 + w*16 + sr)*K + sc;
  const ushort_t* Bg = W + (size_t)(n0 + w*16 + sr)*K + sc;

#define STAGE(Abuf, Bbuf, kt) do {              \
    gload16(Ag + (kt), &(Abuf)[(w*16)*32]);     \
    gload16(Bg + (kt), &(Bbuf)[(w*16)*32]);     \
  } while(0)

#define COMPUTE(Abuf, Bbuf) do {                                             \
    short8 bfr[4];                                                           \
    _Pragma("unroll")                                                        \
    for (int j=0;j<4;j++)                                                    \
      bfr[j] = *(const short8*)&(Bbuf)[(wn*64 + j*16)*32 + fidx];            \
    short8 afr[2];                                                           \
    _Pragma("unroll")                                                        \
    for (int mi=0; mi<2; mi++)                                               \
      afr[mi] = *(const short8*)&(Abuf)[(wm*32 + mi*16)*32 + fidx];          \
    __builtin_amdgcn_s_setprio(1);                                           \
    _Pragma("unroll")                                                        \
    for (int mi=0; mi<2; mi++)                                               \
      _Pragma("unroll")                                                      \
      for (int j=0;j<4;j++)                                                  \
        acc[mi][j] = __builtin_amdgcn_mfma_f32_16x16x32_bf16(afr[mi], bfr[j], acc[mi][j], 0,0,0); \
    __builtin_amdgcn_s_setprio(0);                                           \
  } while(0)

  const int nt = K >> 5;               // 32 K-tiles
  STAGE(a0, b0, 0);
  STAGE(a1, b1, 32);

  for (int t = 0; t < nt; ++t){
    if (t == nt-1) asm volatile("s_waitcnt vmcnt(0)" ::: "memory");
    else           asm volatile("s_waitcnt vmcnt(2)" ::: "memory");
    asm volatile("s_barrier" ::: "memory");
    if (t+2 < nt) STAGE(a2, b2, (t+2)*32);
    COMPUTE(a0, b0);
    ushort_t* ta = a0; a0 = a1; a1 = a2; a2 = ta;
    ushort_t* tb = b0; b0 = b1; b1 = b2; b2 = tb;
  }
#undef STAGE
#undef COMPUTE

  __syncthreads();

  // coalesced epilogue: C-tile 128x128 bf16 (32KB) in slab
#pragma unroll
  for (int j=0;j<4;j++){
    const int col = wn*64 + j*16 + lr;
    float scale = 1.0f;
    if (MODE==1){
      const int gcol = n0 + col;
      if (gcol < 1024){ float p = pds[gcol & (DH-1)]; scale = qsc * log1pf(expf(p)); }
      else if (gcol < 2048) scale = ksc;
    }
#pragma unroll
    for (int mi=0; mi<2; mi++){
      const int row = wm*32 + mi*16 + lg*4;
#pragma unroll
      for (int r=0;r<4;r++)
        slab[(row + r)*128 + col] = f2bf(acc[mi][j][r] * scale);
    }
  }
  __syncthreads();
  ushort_t* Crow = C + (size_t)m0*N + n0;
  const int rr = tid >> 4, sl = (tid & 15)*8;
#pragma unroll
  for (int it=0; it<4; ++it){
    const int row = it*32 + rr;
    *(short8*)&Crow[(size_t)row*N + sl] = *(const short8*)&slab[row*128 + sl];
  }
}

// ===== r12 gemm3 (16x16 core, 2-way placement) — out-projection =====
template<int MODE, int OUTF>
__global__ __launch_bounds__(256) void gemm3(
    const ushort_t* __restrict__ A, const ushort_t* __restrict__ W,
    void* __restrict__ Cv, int M, int N, int K,
    const float* __restrict__ pds, float qsc, float ksc)
{
  const int nwg  = gridDim.x;
  const int orig = blockIdx.x;
  const int qch  = nwg >> 3, rch = nwg & 7;
  const int xcd  = orig & 7, idx = orig >> 3;
  const int bid  = (xcd < rch ? xcd*(qch+1) : rch*(qch+1) + (xcd-rch)*qch) + idx;

  const int NT = N >> 7;
  const int m0 = (bid / NT) * 128;
  const int n0 = (bid % NT) * 128;

  const int tid  = threadIdx.x;
  const int w    = tid >> 6, lane = tid & 63;
  const int wm   = w >> 1, wn = w & 1;
  const int lr   = lane & 15;
  const int lg   = lane >> 4;

  __shared__ ushort_t slab[6*128*32];
  ushort_t* a0 = slab;                 ushort_t* b0 = slab + 128*32;
  ushort_t* a1 = slab + 2*128*32;      ushort_t* b1 = slab + 3*128*32;
  ushort_t* a2 = slab + 4*128*32;      ushort_t* b2 = slab + 5*128*32;

  float4v acc[4][4];
#pragma unroll
  for (int i=0;i<4;i++)
#pragma unroll
    for (int j=0;j<4;j++) acc[i][j] = (float4v)0.0f;

  const int sr = lane >> 2;
  const int sc = ((lane & 3) ^ ((lane >> 3) & 3)) * 8;
  const int fidx = ((lr >> 1)*8 + (lr & 1)*4 + (lg ^ ((lr >> 1) & 3))) * 8;

  const ushort_t* Ab0 = A + (size_t)(m0 + w*16      + sr)*K + sc;
  const ushort_t* Ab1 = A + (size_t)(m0 + 64 + w*16 + sr)*K + sc;
  const ushort_t* Bb0 = W + (size_t)(n0 + w*16      + sr)*K + sc;
  const ushort_t* Bb1 = W + (size_t)(n0 + 64 + w*16 + sr)*K + sc;

#define STAGE(Abuf, Bbuf, kt) do {                    \
    gload16(Ab0 + (kt), &(Abuf)[(w*16)*32]);          \
    gload16(Ab1 + (kt), &(Abuf)[(64 + w*16)*32]);     \
    gload16(Bb0 + (kt), &(Bbuf)[(w*16)*32]);          \
    gload16(Bb1 + (kt), &(Bbuf)[(64 + w*16)*32]);     \
  } while(0)

#define COMPUTE(Abuf, Bbuf) do {                                             \
    short8 afr[4], bfr[4];                                                   \
    _Pragma("unroll")                                                        \
    for (int i=0;i<4;i++) afr[i] = *(const short8*)&(Abuf)[(wm*4 + i)*512 + fidx]; \
    _Pragma("unroll")                                                        \
    for (int j=0;j<4;j++) bfr[j] = *(const short8*)&(Bbuf)[(wn*4 + j)*512 + fidx]; \
    __builtin_amdgcn_s_setprio(1);                                           \
    _Pragma("unroll")                                                        \
    for (int i=0;i<4;i++)                                                    \
      _Pragma("unroll")                                                      \
      for (int j=0;j<4;j++)                                                  \
        acc[i][j] = __builtin_amdgcn_mfma_f32_16x16x32_bf16(afr[i], bfr[j], acc[i][j], 0,0,0); \
    __builtin_amdgcn_s_setprio(0);                                           \
  } while(0)

  const int nt = K >> 5;
  STAGE(a0, b0, 0);
  STAGE(a1, b1, 32);

  for (int t = 0; t < nt; ++t){
    if (t == nt-1) asm volatile("s_waitcnt vmcnt(0)" ::: "memory");
    else           asm volatile("s_waitcnt vmcnt(4)" ::: "memory");
    asm volatile("s_barrier" ::: "memory");
    if (t+2 < nt) STAGE(a2, b2, (t+2)*32);
    COMPUTE(a0, b0);
    ushort_t* ta = a0; a0 = a1; a1 = a2; a2 = ta;
    ushort_t* tb = b0; b0 = b1; b1 = b2; b2 = tb;
  }
#undef STAGE
#undef COMPUTE

  __syncthreads();

  if (OUTF == 0){
#pragma unroll
    for (int j=0;j<4;j++){
      const int col = wn*64 + j*16 + lr;
      float scale = 1.0f;
      if (MODE==1){
        const int gcol = n0 + col;
        if (gcol < 1024){ float p = pds[gcol & (DH-1)]; scale = qsc * log1pf(expf(p)); }
        else if (gcol < 2048) scale = ksc;
      }
#pragma unroll
      for (int i=0;i<4;i++){
        const int row = wm*64 + i*16 + lg*4;
#pragma unroll
        for (int r=0;r<4;r++)
          slab[(row + r)*128 + col] = f2bf(acc[i][j][r] * scale);
      }
    }
    __syncthreads();
    ushort_t* Crow = (ushort_t*)Cv + (size_t)m0*N + n0;
    const int rr = tid >> 4, sl = (tid & 15)*8;
#pragma unroll
    for (int it=0; it<8; ++it){
      const int row = it*16 + rr;
      *(short8*)&Crow[(size_t)row*N + sl] = *(const short8*)&slab[row*128 + sl];
    }
  } else {
    float* smf = (float*)slab;
    float* Crow = (float*)Cv + (size_t)m0*N + n0;
#pragma unroll
    for (int h2=0; h2<2; ++h2){
      __syncthreads();
      if (wm == h2){
#pragma unroll
        for (int j=0;j<4;j++){
          const int col = wn*64 + j*16 + lr;
#pragma unroll
          for (int i=0;i<4;i++){
            const int row = i*16 + lg*4;
#pragma unroll
            for (int r=0;r<4;r++)
              smf[(row + r)*128 + col] = acc[i][j][r];
          }
        }
      }
      __syncthreads();
      const int rr = tid >> 5, half = ((tid >> 4) & 1)*64, sl = (tid & 15)*4;
#pragma unroll
      for (int it=0; it<8; ++it){
        const int row = it*8 + rr;
        *(float4v*)&Crow[(size_t)(h2*64 + row)*N + half + sl] =
            *(const float4v*)&smf[row*128 + half + sl];
      }
    }
  }
}

// rel[25,1024] = pe[25,1024] @ Wrel^T, 2-way K-split + shfl combine
__global__ __launch_bounds__(256) void relk2(
    const float* __restrict__ pe, const float* __restrict__ Wrel,
    ushort_t* __restrict__ rel)
{
  int g = blockIdx.x*256 + threadIdx.x;
  int idx = g >> 1, par = g & 1;
  if (idx >= NPOS*HID) return;
  int p = idx >> 10, n = idx & 1023;
  const float* a = pe + p*HID + par*512;
  const float* w = Wrel + (size_t)n*HID + par*512;
  float s = 0.f;
  for (int k=0;k<512;k+=4){
    float4v av = *(const float4v*)(a+k);
    float4v wv = *(const float4v*)(w+k);
#pragma unroll
    for (int u=0;u<4;u++) s += av[u]*wv[u];
  }
  s += __shfl_xor(s, 1, 64);
  if (!par) rel[idx] = f2bf(s);
}

// MFMA attention, LDS lifetime-aliased: 49.6KB -> 3 blocks/CU. (r11/r12 passing)
__global__ __launch_bounds__(256) void attn_kernel(
  const ushort_t* __restrict__ qkv, const ushort_t* __restrict__ rel,
  ushort_t* __restrict__ o, int S)
{
  const int n0 = blockIdx.x * 4;
  const int b  = blockIdx.y, h = blockIdx.z;
  const int tid = threadIdx.x;
  const size_t bS = (size_t)b * S;

  __shared__ ushort_t lds[24800];
  ushort_t* ks = lds;
  ushort_t* vt = lds + 9248;
  float*    sB = (float*)(lds + 17952);
  ushort_t* rs = lds + 20448;
  float*    sA = (float*)(lds + 20448);

  const int base = n0*CHUNK - PAST;
  {
    const int r0 = tid >> 4;
    const int c0 = (tid & 15) * 8;
    for (int r = r0; r < 68; r += 16){
      int s = base + r;
      short8 kv = (short8)0, vv = (short8)0;
      if (r < 60 && s >= 0 && s < S){
        kv = *(const short8*)&qkv[(bS + s)*QKVW + 1024 + h*DH + c0];
        vv = *(const short8*)&qkv[(bS + s)*QKVW + 2048 + h*DH + c0];
      }
      *(short8*)&ks[r*136 + c0] = kv;
#pragma unroll
      for (int u=0;u<8;u++) vt[(c0+u)*68 + r] = (ushort_t)vv[u];
    }
    for (int r = r0; r < 32; r += 16){
      short8 rv = (short8)0;
      if (r < NPOS) rv = *(const short8*)&rel[r*HID + h*DH + c0];
      *(short8*)&rs[r*136 + c0] = rv;
    }
  }
  __syncthreads();

  const int w    = tid >> 6;
  const int lane = tid & 63;
  const int lr   = lane & 15;
  const int lg   = lane >> 4;

  float*    sAw = sA + w*312;
  float*    sBw = sB + w*312;
  ushort_t* Ppw = lds + w*640;

  int qrow = (n0 + w)*CHUNK + lr;
  if (qrow >= S) qrow = S - 1;
  const ushort_t* qp = qkv + (bS + qrow)*QKVW + h*DH + lg*8;
  short8 qf[4];
#pragma unroll
  for (int ks2=0; ks2<4; ks2++) qf[ks2] = *(const short8*)(qp + ks2*32);

  // BD = q @ rel^T
#pragma unroll
  for (int t0=0; t0<2; t0++){
    float4v acc = (float4v)0.0f;
#pragma unroll
    for (int ks2=0; ks2<4; ks2++){
      short8 rf = *(const short8*)&rs[(t0*16 + lr)*136 + ks2*32 + lg*8];
      acc = __builtin_amdgcn_mfma_f32_16x16x32_bf16(qf[ks2], rf, acc, 0,0,0);
    }
    const int p = t0*16 + lr;
#pragma unroll
    for (int reg=0; reg<4; reg++){
      int cr = lg*4 + reg;
      if (cr < CHUNK && p < NPOS) sBw[cr*26 + p] = acc[reg];
    }
  }
  __syncthreads();

  // AC = q @ k^T (sA aliases rs)
#pragma unroll
  for (int t0=0; t0<2; t0++){
    float4v acc = (float4v)0.0f;
#pragma unroll
    for (int ks2=0; ks2<4; ks2++){
      short8 kf = *(const short8*)&ks[(w*CHUNK + t0*16 + lr)*136 + ks2*32 + lg*8];
      acc = __builtin_amdgcn_mfma_f32_16x16x32_bf16(qf[ks2], kf, acc, 0,0,0);
    }
    const int t = t0*16 + lr;
#pragma unroll
    for (int reg=0; reg<4; reg++){
      int cr = lg*4 + reg;
      if (cr < CHUNK && t < CTX) sAw[cr*26 + t] = acc[reg];
    }
  }
  __syncthreads();

  if (lane < CHUNK) *(short8*)&Ppw[lane*40 + 24] = (short8)0;

  {
    const int c2 = lane >> 5;
    const int t  = lane & 31;
#pragma unroll
    for (int i=0;i<6;i++){
      int c = i*2 + c2;
      float x = -1e30f;
      if (t < CTX){
        int f = c*CTX + t;
        int r = f / NPOS, p = f - r*NPOS;
        x = sAw[c*26 + t] + sBw[r*26 + p];
        x = 50.0f * tanhf(x * 0.02f);
      }
      float m = x;
      for (int off=16; off>=1; off>>=1) m = fmaxf(m, __shfl_xor(m, off, 32));
      float e = (t < CTX) ? expf(x - m) : 0.0f;
      float s = e;
      for (int off=16; off>=1; off>>=1) s += __shfl_xor(s, off, 32);
      if (t < CTX) Ppw[c*40 + t] = f2bf(e / s);
    }
  }

  short8 pf = *(const short8*)&Ppw[lr*40 + lg*8];
  const int orow_base = (n0 + w)*CHUNK;
#pragma unroll
  for (int j=0; j<8; j++){
    int d  = j*16 + lr;
    int tb = w*CHUNK + lg*8;
    s4v b0 = *(const s4v*)&vt[d*68 + tb];
    s4v b1 = *(const s4v*)&vt[d*68 + tb + 4];
    short8 bf;
#pragma unroll
    for (int u=0;u<4;u++){ bf[u] = b0[u]; bf[u+4] = b1[u]; }
    float4v a = __builtin_amdgcn_mfma_f32_16x16x32_bf16(pf, bf, (float4v)0.0f, 0,0,0);
#pragma unroll
    for (int reg=0; reg<4; reg++){
      int cr = lg*4 + reg;
      if (cr < CHUNK)
        o[(bS + orow_base + cr)*HID + h*DH + j*16 + lr] = f2bf(a[reg]);
    }
  }
}

extern "C" void kernel_launch(void* const* d_in, const int* in_sizes, int n_in,
                              void* d_out, int out_size, void* d_ws, size_t ws_size,
                              hipStream_t stream)
{
  const float* hs    = (const float*)d_in[0];
  const float* pe    = (const float*)d_in[1];
  const float* Wq    = (const float*)d_in[2];
  const float* Wk    = (const float*)d_in[3];
  const float* Wv    = (const float*)d_in[4];
  const float* Wpost = (const float*)d_in[5];
  const float* Wrel  = (const float*)d_in[6];
  const float* pds   = (const float*)d_in[7];
  float* out = (float*)d_out;

  const int BS = in_sizes[0] / HID;   // 24576
  const int B  = 4;
  const int S  = BS / B;              // 6144
  const int nb = S / CHUNK;           // 512

  const size_t per = (size_t)BS * HID;
  const size_t wsz = (size_t)HID * HID;
  ushort_t* qkv  = (ushort_t*)d_ws;
  ushort_t* at   = qkv  + (size_t)BS * QKVW;
  ushort_t* rel  = at   + per;
  ushort_t* hsb  = rel  + (size_t)NPOS*HID;
  ushort_t* Wcat = hsb  + per;
  ushort_t* Wpb  = Wcat + 3*wsz;

  const float qsc = (float)(pow((double)DH, -0.5) / log(2.0));
  const float ksc = (float)(log(1.0 + exp(1.0)) / log(2.0));

  cvt_all<<<4096, 256, 0, stream>>>(hs, Wq, Wk, Wv, Wpost, hsb, Wcat, Wpb,
                                    (int)(per/4));
  relk2<<<200, 256, 0, stream>>>(pe, Wrel, rel);

  // fused QKV projection: 128^2 tile, 8 waves of 32x64
  gemm8w<1><<<(BS/128)*(QKVW/128), 512, 0, stream>>>(
      hsb, Wcat, qkv, BS, QKVW, HID, pds, qsc, ksc);
  attn_kernel<<<dim3(nb/4, B, NH), 256, 0, stream>>>(qkv, rel, at, S);
  // output projection (r12 gemm3)
  gemm3<0,1><<<(BS/128)*(HID/128), 256, 0, stream>>>(
      at, Wpb, out, BS, HID, HID, nullptr, 1.0f, 1.0f);
}

// Round 16
// 375.904 us; speedup vs baseline: 1.0674x; 1.0358x over previous
//
#include <hip/hip_runtime.h>
#include <hip/hip_bf16.h>
#include <math.h>

typedef unsigned short ushort_t;
typedef __attribute__((ext_vector_type(8))) short short8;
typedef __attribute__((ext_vector_type(4))) short s4v;
typedef __attribute__((ext_vector_type(4))) float float4v;

#define HID 1024
#define NH 8
#define DH 128
#define CHUNK 12
#define PAST 12
#define CTX 24
#define NPOS 25
#define QKVW 3072

__device__ __forceinline__ float bf2f(ushort_t b){
  union{unsigned int u; float f;} x; x.u = ((unsigned int)b)<<16; return x.f;
}
__device__ __forceinline__ ushort_t f2bf(float f){
  union{float f; unsigned int u;} x; x.f = f;
  unsigned int u = x.u;
  unsigned int r = u + 0x7fffu + ((u>>16)&1u);
  return (ushort_t)(r>>16);
}

__device__ __forceinline__ void gload16(const ushort_t* g, ushort_t* l){
  __builtin_amdgcn_global_load_lds(
      (const __attribute__((address_space(1))) unsigned int*)g,
      (__attribute__((address_space(3))) unsigned int*)l,
      16, 0, 0);
}

// ===== merged prep: relk (items first) + f32->bf16 conversions =====
// relk items = 51200 = 800 full waves -> no intra-wave divergence; the
// small rel GEMM hides under the 150MB hs conversion stream.
__global__ __launch_bounds__(256) void prep_all(
    const float* __restrict__ hs, const float* __restrict__ pe,
    const float* __restrict__ Wq, const float* __restrict__ Wk,
    const float* __restrict__ Wv, const float* __restrict__ Wp,
    const float* __restrict__ Wrel,
    ushort_t* __restrict__ hsb, ushort_t* __restrict__ Wcat,
    ushort_t* __restrict__ Wpb, ushort_t* __restrict__ rel, int nhs4)
{
  const int W4 = 262144;               // (1024*1024)/4
  const int NRELK = NPOS*HID*2;        // 51200
  const int total = NRELK + nhs4 + 4*W4;
  for (int i = blockIdx.x*256 + threadIdx.x; i < total; i += gridDim.x*256){
    if (i < NRELK){
      const int idx = i >> 1, par = i & 1;
      const int p = idx >> 10, n = idx & 1023;
      const float* a = pe + p*HID + par*512;
      const float* w = Wrel + (size_t)n*HID + par*512;
      float s = 0.f;
      for (int k=0;k<512;k+=4){
        float4v av = *(const float4v*)(a+k);
        float4v wv = *(const float4v*)(w+k);
#pragma unroll
        for (int u=0;u<4;u++) s += av[u]*wv[u];
      }
      s += __shfl_xor(s, 1, 64);
      if (!par) rel[idx] = f2bf(s);
      continue;
    }
    const int ic = i - NRELK;
    const float4v* src; s4v* dst; int off;
    if (ic < nhs4){ src = (const float4v*)hs; dst = (s4v*)hsb; off = ic; }
    else {
      int j = ic - nhs4; int seg = j >> 18; off = j & (W4-1);
      src = (const float4v*)(seg==0?Wq:seg==1?Wk:seg==2?Wv:Wp);
      dst = (seg<3) ? ((s4v*)Wcat) + (size_t)seg*W4 : (s4v*)Wpb;
    }
    float4v v = src[off];
    s4v o;
#pragma unroll
    for (int j2=0;j2<4;j2++) o[j2] = (short)f2bf(v[j2]);
    dst[off] = o;
  }
}

// ===== r12 gemm3: 128x128 BK=32 3-slot-ring counted-vmcnt, 2-way placement =====
template<int MODE, int OUTF>
__global__ __launch_bounds__(256) void gemm3(
    const ushort_t* __restrict__ A, const ushort_t* __restrict__ W,
    void* __restrict__ Cv, int M, int N, int K,
    const float* __restrict__ pds, float qsc, float ksc)
{
  const int nwg  = gridDim.x;
  const int orig = blockIdx.x;
  const int qch  = nwg >> 3, rch = nwg & 7;
  const int xcd  = orig & 7, idx = orig >> 3;
  const int bid  = (xcd < rch ? xcd*(qch+1) : rch*(qch+1) + (xcd-rch)*qch) + idx;

  const int NT = N >> 7;
  const int m0 = (bid / NT) * 128;
  const int n0 = (bid % NT) * 128;

  const int tid  = threadIdx.x;
  const int w    = tid >> 6, lane = tid & 63;
  const int wm   = w >> 1, wn = w & 1;
  const int lr   = lane & 15;
  const int lg   = lane >> 4;

  __shared__ ushort_t slab[6*128*32];          // 48KB: 3 x (A,B)
  ushort_t* a0 = slab;                 ushort_t* b0 = slab + 128*32;
  ushort_t* a1 = slab + 2*128*32;      ushort_t* b1 = slab + 3*128*32;
  ushort_t* a2 = slab + 4*128*32;      ushort_t* b2 = slab + 5*128*32;

  float4v acc[4][4];
#pragma unroll
  for (int i=0;i<4;i++)
#pragma unroll
    for (int j=0;j<4;j++) acc[i][j] = (float4v)0.0f;

  const int sr = lane >> 2;
  const int sc = ((lane & 3) ^ ((lane >> 3) & 3)) * 8;
  const int fidx = ((lr >> 1)*8 + (lr & 1)*4 + (lg ^ ((lr >> 1) & 3))) * 8;

  const ushort_t* Ab0 = A + (size_t)(m0 + w*16      + sr)*K + sc;
  const ushort_t* Ab1 = A + (size_t)(m0 + 64 + w*16 + sr)*K + sc;
  const ushort_t* Bb0 = W + (size_t)(n0 + w*16      + sr)*K + sc;
  const ushort_t* Bb1 = W + (size_t)(n0 + 64 + w*16 + sr)*K + sc;

#define STAGE(Abuf, Bbuf, kt) do {                    \
    gload16(Ab0 + (kt), &(Abuf)[(w*16)*32]);          \
    gload16(Ab1 + (kt), &(Abuf)[(64 + w*16)*32]);     \
    gload16(Bb0 + (kt), &(Bbuf)[(w*16)*32]);          \
    gload16(Bb1 + (kt), &(Bbuf)[(64 + w*16)*32]);     \
  } while(0)

#define COMPUTE(Abuf, Bbuf) do {                                             \
    short8 afr[4], bfr[4];                                                   \
    _Pragma("unroll")                                                        \
    for (int i=0;i<4;i++) afr[i] = *(const short8*)&(Abuf)[(wm*4 + i)*512 + fidx]; \
    _Pragma("unroll")                                                        \
    for (int j=0;j<4;j++) bfr[j] = *(const short8*)&(Bbuf)[(wn*4 + j)*512 + fidx]; \
    __builtin_amdgcn_s_setprio(1);                                           \
    _Pragma("unroll")                                                        \
    for (int i=0;i<4;i++)                                                    \
      _Pragma("unroll")                                                      \
      for (int j=0;j<4;j++)                                                  \
        acc[i][j] = __builtin_amdgcn_mfma_f32_16x16x32_bf16(afr[i], bfr[j], acc[i][j], 0,0,0); \
    __builtin_amdgcn_s_setprio(0);                                           \
  } while(0)

  const int nt = K >> 5;
  STAGE(a0, b0, 0);
  STAGE(a1, b1, 32);

  for (int t = 0; t < nt; ++t){
    if (t == nt-1) asm volatile("s_waitcnt vmcnt(0)" ::: "memory");
    else           asm volatile("s_waitcnt vmcnt(4)" ::: "memory");
    asm volatile("s_barrier" ::: "memory");
    if (t+2 < nt) STAGE(a2, b2, (t+2)*32);
    COMPUTE(a0, b0);
    ushort_t* ta = a0; a0 = a1; a1 = a2; a2 = ta;
    ushort_t* tb = b0; b0 = b1; b1 = b2; b2 = tb;
  }
#undef STAGE
#undef COMPUTE

  __syncthreads();

  if (OUTF == 0){
#pragma unroll
    for (int j=0;j<4;j++){
      const int col = wn*64 + j*16 + lr;
      float scale = 1.0f;
      if (MODE==1){
        const int gcol = n0 + col;
        if (gcol < 1024){ float p = pds[gcol & (DH-1)]; scale = qsc * log1pf(expf(p)); }
        else if (gcol < 2048) scale = ksc;
      }
#pragma unroll
      for (int i=0;i<4;i++){
        const int row = wm*64 + i*16 + lg*4;
#pragma unroll
        for (int r=0;r<4;r++)
          slab[(row + r)*128 + col] = f2bf(acc[i][j][r] * scale);
      }
    }
    __syncthreads();
    ushort_t* Crow = (ushort_t*)Cv + (size_t)m0*N + n0;
    const int rr = tid >> 4, sl = (tid & 15)*8;
#pragma unroll
    for (int it=0; it<8; ++it){
      const int row = it*16 + rr;
      *(short8*)&Crow[(size_t)row*N + sl] = *(const short8*)&slab[row*128 + sl];
    }
  } else {
    float* smf = (float*)slab;
    float* Crow = (float*)Cv + (size_t)m0*N + n0;
#pragma unroll
    for (int h2=0; h2<2; ++h2){
      __syncthreads();
      if (wm == h2){
#pragma unroll
        for (int j=0;j<4;j++){
          const int col = wn*64 + j*16 + lr;
#pragma unroll
          for (int i=0;i<4;i++){
            const int row = i*16 + lg*4;
#pragma unroll
            for (int r=0;r<4;r++)
              smf[(row + r)*128 + col] = acc[i][j][r];
          }
        }
      }
      __syncthreads();
      const int rr = tid >> 5, half = ((tid >> 4) & 1)*64, sl = (tid & 15)*4;
#pragma unroll
      for (int it=0; it<8; ++it){
        const int row = it*8 + rr;
        *(float4v*)&Crow[(size_t)(h2*64 + row)*N + half + sl] =
            *(const float4v*)&smf[row*128 + half + sl];
      }
    }
  }
}

// MFMA attention, LDS lifetime-aliased: 49.6KB -> 3 blocks/CU. (r11/r12 passing)
__global__ __launch_bounds__(256) void attn_kernel(
  const ushort_t* __restrict__ qkv, const ushort_t* __restrict__ rel,
  ushort_t* __restrict__ o, int S)
{
  const int n0 = blockIdx.x * 4;
  const int b  = blockIdx.y, h = blockIdx.z;
  const int tid = threadIdx.x;
  const size_t bS = (size_t)b * S;

  __shared__ ushort_t lds[24800];
  ushort_t* ks = lds;
  ushort_t* vt = lds + 9248;
  float*    sB = (float*)(lds + 17952);
  ushort_t* rs = lds + 20448;
  float*    sA = (float*)(lds + 20448);

  const int base = n0*CHUNK - PAST;
  {
    const int r0 = tid >> 4;
    const int c0 = (tid & 15) * 8;
    for (int r = r0; r < 68; r += 16){
      int s = base + r;
      short8 kv = (short8)0, vv = (short8)0;
      if (r < 60 && s >= 0 && s < S){
        kv = *(const short8*)&qkv[(bS + s)*QKVW + 1024 + h*DH + c0];
        vv = *(const short8*)&qkv[(bS + s)*QKVW + 2048 + h*DH + c0];
      }
      *(short8*)&ks[r*136 + c0] = kv;
#pragma unroll
      for (int u=0;u<8;u++) vt[(c0+u)*68 + r] = (ushort_t)vv[u];
    }
    for (int r = r0; r < 32; r += 16){
      short8 rv = (short8)0;
      if (r < NPOS) rv = *(const short8*)&rel[r*HID + h*DH + c0];
      *(short8*)&rs[r*136 + c0] = rv;
    }
  }
  __syncthreads();

  const int w    = tid >> 6;
  const int lane = tid & 63;
  const int lr   = lane & 15;
  const int lg   = lane >> 4;

  float*    sAw = sA + w*312;
  float*    sBw = sB + w*312;
  ushort_t* Ppw = lds + w*640;

  int qrow = (n0 + w)*CHUNK + lr;
  if (qrow >= S) qrow = S - 1;
  const ushort_t* qp = qkv + (bS + qrow)*QKVW + h*DH + lg*8;
  short8 qf[4];
#pragma unroll
  for (int ks2=0; ks2<4; ks2++) qf[ks2] = *(const short8*)(qp + ks2*32);

  // BD = q @ rel^T
#pragma unroll
  for (int t0=0; t0<2; t0++){
    float4v acc = (float4v)0.0f;
#pragma unroll
    for (int ks2=0; ks2<4; ks2++){
      short8 rf = *(const short8*)&rs[(t0*16 + lr)*136 + ks2*32 + lg*8];
      acc = __builtin_amdgcn_mfma_f32_16x16x32_bf16(qf[ks2], rf, acc, 0,0,0);
    }
    const int p = t0*16 + lr;
#pragma unroll
    for (int reg=0; reg<4; reg++){
      int cr = lg*4 + reg;
      if (cr < CHUNK && p < NPOS) sBw[cr*26 + p] = acc[reg];
    }
  }
  __syncthreads();

  // AC = q @ k^T (sA aliases rs)
#pragma unroll
  for (int t0=0; t0<2; t0++){
    float4v acc = (float4v)0.0f;
#pragma unroll
    for (int ks2=0; ks2<4; ks2++){
      short8 kf = *(const short8*)&ks[(w*CHUNK + t0*16 + lr)*136 + ks2*32 + lg*8];
      acc = __builtin_amdgcn_mfma_f32_16x16x32_bf16(qf[ks2], kf, acc, 0,0,0);
    }
    const int t = t0*16 + lr;
#pragma unroll
    for (int reg=0; reg<4; reg++){
      int cr = lg*4 + reg;
      if (cr < CHUNK && t < CTX) sAw[cr*26 + t] = acc[reg];
    }
  }
  __syncthreads();

  if (lane < CHUNK) *(short8*)&Ppw[lane*40 + 24] = (short8)0;

  {
    const int c2 = lane >> 5;
    const int t  = lane & 31;
#pragma unroll
    for (int i=0;i<6;i++){
      int c = i*2 + c2;
      float x = -1e30f;
      if (t < CTX){
        int f = c*CTX + t;
        int r = f / NPOS, p = f - r*NPOS;
        x = sAw[c*26 + t] + sBw[r*26 + p];
        x = 50.0f * tanhf(x * 0.02f);
      }
      float m = x;
      for (int off=16; off>=1; off>>=1) m = fmaxf(m, __shfl_xor(m, off, 32));
      float e = (t < CTX) ? expf(x - m) : 0.0f;
      float s = e;
      for (int off=16; off>=1; off>>=1) s += __shfl_xor(s, off, 32);
      if (t < CTX) Ppw[c*40 + t] = f2bf(e / s);
    }
  }

  short8 pf = *(const short8*)&Ppw[lr*40 + lg*8];
  const int orow_base = (n0 + w)*CHUNK;
#pragma unroll
  for (int j=0; j<8; j++){
    int d  = j*16 + lr;
    int tb = w*CHUNK + lg*8;
    s4v b0 = *(const s4v*)&vt[d*68 + tb];
    s4v b1 = *(const s4v*)&vt[d*68 + tb + 4];
    short8 bf;
#pragma unroll
    for (int u=0;u<4;u++){ bf[u] = b0[u]; bf[u+4] = b1[u]; }
    float4v a = __builtin_amdgcn_mfma_f32_16x16x32_bf16(pf, bf, (float4v)0.0f, 0,0,0);
#pragma unroll
    for (int reg=0; reg<4; reg++){
      int cr = lg*4 + reg;
      if (cr < CHUNK)
        o[(bS + orow_base + cr)*HID + h*DH + j*16 + lr] = f2bf(a[reg]);
    }
  }
}

extern "C" void kernel_launch(void* const* d_in, const int* in_sizes, int n_in,
                              void* d_out, int out_size, void* d_ws, size_t ws_size,
                              hipStream_t stream)
{
  const float* hs    = (const float*)d_in[0];
  const float* pe    = (const float*)d_in[1];
  const float* Wq    = (const float*)d_in[2];
  const float* Wk    = (const float*)d_in[3];
  const float* Wv    = (const float*)d_in[4];
  const float* Wpost = (const float*)d_in[5];
  const float* Wrel  = (const float*)d_in[6];
  const float* pds   = (const float*)d_in[7];
  float* out = (float*)d_out;

  const int BS = in_sizes[0] / HID;   // 24576
  const int B  = 4;
  const int S  = BS / B;              // 6144
  const int nb = S / CHUNK;           // 512

  const size_t per = (size_t)BS * HID;
  const size_t wsz = (size_t)HID * HID;
  ushort_t* qkv  = (ushort_t*)d_ws;
  ushort_t* at   = qkv  + (size_t)BS * QKVW;
  ushort_t* rel  = at   + per;
  ushort_t* hsb  = rel  + (size_t)NPOS*HID;
  ushort_t* Wcat = hsb  + per;
  ushort_t* Wpb  = Wcat + 3*wsz;

  const float qsc = (float)(pow((double)DH, -0.5) / log(2.0));
  const float ksc = (float)(log(1.0 + exp(1.0)) / log(2.0));

  // merged conversions + rel GEMM (relk items first in index space)
  prep_all<<<4096, 256, 0, stream>>>(hs, pe, Wq, Wk, Wv, Wpost, Wrel,
                                     hsb, Wcat, Wpb, rel, (int)(per/4));

  // fused QKV projection: [24576,1024] @ [3072,1024]^T -> qkv
  gemm3<1,0><<<(BS/128)*(QKVW/128), 256, 0, stream>>>(
      hsb, Wcat, qkv, BS, QKVW, HID, pds, qsc, ksc);
  attn_kernel<<<dim3(nb/4, B, NH), 256, 0, stream>>>(qkv, rel, at, S);
  // output projection: [24576,1024] @ [1024,1024]^T -> out (f32)
  gemm3<0,1><<<(BS/128)*(HID/128), 256, 0, stream>>>(
      at, Wpb, out, BS, HID, HID, nullptr, 1.0f, 1.0f);
}